// Round 3
// baseline (137.515 us; speedup 1.0000x reference)
//
#include <hip/hip_runtime.h>
#include <cstddef>

#define ZDIM 64
#define PDIM 4096          // Z*Z
#define PB   256           // p's per block (= blockDim)
#define BCHUNK 32          // batch rows per block (processed 4 at a time)

typedef float v2f __attribute__((ext_vector_type(2)));

__device__ __forceinline__ v2f pkfma(v2f a, v2f b, v2f c) {
    return __builtin_elementwise_fma(a, b, c);
}

__device__ __forceinline__ v2f splat(float s) { v2f r; r.x = s; r.y = s; return r; }

// Odd Pade(7,6) tanh: valid (<1e-4 abs err) for |x| <= ~5.5; our inputs are
// analytically bounded to |x| <= ~4.5 (see theory), so no clamp needed.
__device__ __forceinline__ v2f tanh2(v2f x) {
    v2f t = x * x;
    v2f np = t + splat(378.0f);
    np = pkfma(np, t, splat(17325.0f));
    np = pkfma(np, t, splat(135135.0f));
    v2f dp = pkfma(splat(28.0f), t, splat(3150.0f));
    dp = pkfma(dp, t, splat(62370.0f));
    dp = pkfma(dp, t, splat(135135.0f));
    v2f num = x * np;
    v2f r; r.x = __builtin_amdgcn_rcpf(dp.x); r.y = __builtin_amdgcn_rcpf(dp.y);
    return num * r;
}

__device__ __forceinline__ float fast_sigmoid(float x) {
    float e = __builtin_amdgcn_exp2f(x * -1.4426950408889634f);
    return __builtin_amdgcn_rcpf(e + 1.0f);
}

__global__ void __launch_bounds__(PB, 4) pair_mlp_kernel(
    const float* __restrict__ x,
    const float* __restrict__ W1, const float* __restrict__ b1,
    const float* __restrict__ g1, const float* __restrict__ be1,
    const float* __restrict__ W2, const float* __restrict__ b2,
    const float* __restrict__ g2, const float* __restrict__ be2,
    const float* __restrict__ W3, const float* __restrict__ b3,
    float* __restrict__ out, int nbc)
{
    const int tid = threadIdx.x;
    const int pb  = blockIdx.x / nbc;          // which p-tile (0..15)
    const int bc  = blockIdx.x - pb * nbc;     // which batch chunk
    const int p   = pb * PB + tid;
    const int z   = __builtin_amdgcn_readfirstlane(p >> 6);  // wave-uniform
    const int zp  = p & 63;

    // ---------------- load per-p weights (once per block) ----------------
    const float4* W1v = reinterpret_cast<const float4*>(W1 + (size_t)p * 8);
    const float4 w1x = W1v[0];   // W1[p][0][0..3]
    const float4 w1y = W1v[1];   // W1[p][1][0..3]
    const float4 b1v  = reinterpret_cast<const float4*>(b1)[p];
    const float4 g1v  = reinterpret_cast<const float4*>(g1)[p];
    const float4 be1v = reinterpret_cast<const float4*>(be1)[p];

    float w2[4][4];
    {
        const float4* W2v = reinterpret_cast<const float4*>(W2 + (size_t)p * 16);
        #pragma unroll
        for (int i = 0; i < 4; ++i) {
            float4 r = W2v[i];
            w2[i][0] = r.x; w2[i][1] = r.y; w2[i][2] = r.z; w2[i][3] = r.w;
        }
    }
    const float4 b2v  = reinterpret_cast<const float4*>(b2)[p];
    const float4 g2v  = reinterpret_cast<const float4*>(g2)[p];
    const float4 be2v = reinterpret_cast<const float4*>(be2)[p];
    const float4 w3v  = reinterpret_cast<const float4*>(W3)[p];
    const float  b3s  = b3[p];

    const float w1aa[4] = {w1x.x, w1x.y, w1x.z, w1x.w};
    const float w1ba[4] = {w1y.x, w1y.y, w1y.z, w1y.w};
    const float b1a[4]  = {b1v.x, b1v.y, b1v.z, b1v.w};
    const float g1a[4]  = {g1v.x, g1v.y, g1v.z, g1v.w};
    const float be1a[4] = {be1v.x, be1v.y, be1v.z, be1v.w};
    const float b2a[4]  = {b2v.x, b2v.y, b2v.z, b2v.w};
    const float g2a[4]  = {g2v.x, g2v.y, g2v.z, g2v.w};
    const float be2a[4] = {be2v.x, be2v.y, be2v.z, be2v.w};
    const float w3a[4]  = {w3v.x, w3v.y, w3v.z, w3v.w};

    // ---- fold LN1 affine into layer 2, LN2 affine into layer 3 ----
    float w2g[4][4], cs2[4], b2p[4];
    #pragma unroll
    for (int j = 0; j < 4; ++j) { cs2[j] = 0.f; b2p[j] = b2a[j]; }
    #pragma unroll
    for (int i = 0; i < 4; ++i) {
        #pragma unroll
        for (int j = 0; j < 4; ++j) {
            float wg = g1a[i] * w2[i][j];
            w2g[i][j] = wg;
            cs2[j] += wg;
            b2p[j] = __builtin_fmaf(be1a[i], w2[i][j], b2p[j]);
        }
    }
    float w3g[4], cs3 = 0.f, b3p = b3s;
    #pragma unroll
    for (int j = 0; j < 4; ++j) {
        w3g[j] = g2a[j] * w3a[j];
        cs3 += w3g[j];
        b3p = __builtin_fmaf(be2a[j], w3a[j], b3p);
    }

    // ---------------- batch loop: 4 rows per iteration (2x v2f) ----------------
    const int b0 = bc * BCHUNK;
    for (int it = 0; it < BCHUNK; it += 4) {
        const int b = b0 + it;
        v2f avA, cvA, avB, cvB;
        avA.x = x[(b + 0) * ZDIM + z];
        avA.y = x[(b + 1) * ZDIM + z];
        avB.x = x[(b + 2) * ZDIM + z];
        avB.y = x[(b + 3) * ZDIM + z];
        cvA.x = x[(b + 0) * ZDIM + zp];
        cvA.y = x[(b + 1) * ZDIM + zp];
        cvB.x = x[(b + 2) * ZDIM + zp];
        cvB.y = x[(b + 3) * ZDIM + zp];

        // layer 1 + tanh
        v2f tA[4], tB[4];
        #pragma unroll
        for (int i = 0; i < 4; ++i) {
            v2f wa = splat(w1aa[i]), wb = splat(w1ba[i]), bb = splat(b1a[i]);
            tA[i] = tanh2(pkfma(avA, wa, pkfma(cvA, wb, bb)));
            tB[i] = tanh2(pkfma(avB, wa, pkfma(cvB, wb, bb)));
        }

        // LN1 moments
        v2f s1A = (tA[0] + tA[1]) + (tA[2] + tA[3]);
        v2f s1B = (tB[0] + tB[1]) + (tB[2] + tB[3]);
        v2f s2A = pkfma(tA[0], tA[0], pkfma(tA[1], tA[1], pkfma(tA[2], tA[2], tA[3] * tA[3])));
        v2f s2B = pkfma(tB[0], tB[0], pkfma(tB[1], tB[1], pkfma(tB[2], tB[2], tB[3] * tB[3])));
        v2f mA  = s1A * 0.25f,  mB  = s1B * 0.25f;
        v2f mnA = s1A * -0.25f, mnB = s1B * -0.25f;
        v2f varA = pkfma(mnA, mA, s2A * 0.25f) + splat(1e-5f);
        v2f varB = pkfma(mnB, mB, s2B * 0.25f) + splat(1e-5f);
        v2f rsA, rsB;
        rsA.x = __builtin_amdgcn_rsqf(varA.x); rsA.y = __builtin_amdgcn_rsqf(varA.y);
        rsB.x = __builtin_amdgcn_rsqf(varB.x); rsB.y = __builtin_amdgcn_rsqf(varB.y);

        // layer 2 (LN1 folded) + tanh
        v2f uA[4], uB[4];
        #pragma unroll
        for (int j = 0; j < 4; ++j) {
            v2f accA = mnA * splat(cs2[j]);
            v2f accB = mnB * splat(cs2[j]);
            #pragma unroll
            for (int i = 0; i < 4; ++i) {
                v2f wg = splat(w2g[i][j]);
                accA = pkfma(tA[i], wg, accA);
                accB = pkfma(tB[i], wg, accB);
            }
            v2f bp = splat(b2p[j]);
            uA[j] = tanh2(pkfma(rsA, accA, bp));
            uB[j] = tanh2(pkfma(rsB, accB, bp));
        }

        // LN2 moments
        v2f q1A = (uA[0] + uA[1]) + (uA[2] + uA[3]);
        v2f q1B = (uB[0] + uB[1]) + (uB[2] + uB[3]);
        v2f q2A = pkfma(uA[0], uA[0], pkfma(uA[1], uA[1], pkfma(uA[2], uA[2], uA[3] * uA[3])));
        v2f q2B = pkfma(uB[0], uB[0], pkfma(uB[1], uB[1], pkfma(uB[2], uB[2], uB[3] * uB[3])));
        v2f m2A  = q1A * 0.25f,  m2B  = q1B * 0.25f;
        v2f mn2A = q1A * -0.25f, mn2B = q1B * -0.25f;
        v2f var2A = pkfma(mn2A, m2A, q2A * 0.25f) + splat(1e-5f);
        v2f var2B = pkfma(mn2B, m2B, q2B * 0.25f) + splat(1e-5f);
        v2f rs2A, rs2B;
        rs2A.x = __builtin_amdgcn_rsqf(var2A.x); rs2A.y = __builtin_amdgcn_rsqf(var2A.y);
        rs2B.x = __builtin_amdgcn_rsqf(var2B.x); rs2B.y = __builtin_amdgcn_rsqf(var2B.y);

        // layer 3 (LN2 folded) + sigmoid
        v2f accA = mn2A * splat(cs3);
        v2f accB = mn2B * splat(cs3);
        #pragma unroll
        for (int j = 0; j < 4; ++j) {
            v2f wg = splat(w3g[j]);
            accA = pkfma(uA[j], wg, accA);
            accB = pkfma(uB[j], wg, accB);
        }
        v2f bp3 = splat(b3p);
        v2f sA = pkfma(rs2A, accA, bp3);
        v2f sB = pkfma(rs2B, accB, bp3);

        out[(size_t)(b + 0) * PDIM + p] = fast_sigmoid(sA.x);
        out[(size_t)(b + 1) * PDIM + p] = fast_sigmoid(sA.y);
        out[(size_t)(b + 2) * PDIM + p] = fast_sigmoid(sB.x);
        out[(size_t)(b + 3) * PDIM + p] = fast_sigmoid(sB.y);
    }
}

extern "C" void kernel_launch(void* const* d_in, const int* in_sizes, int n_in,
                              void* d_out, int out_size, void* d_ws, size_t ws_size,
                              hipStream_t stream) {
    const float* x   = (const float*)d_in[0];
    const float* W1  = (const float*)d_in[1];
    const float* b1  = (const float*)d_in[2];
    const float* g1  = (const float*)d_in[3];
    const float* be1 = (const float*)d_in[4];
    const float* W2  = (const float*)d_in[5];
    const float* b2  = (const float*)d_in[6];
    const float* g2  = (const float*)d_in[7];
    const float* be2 = (const float*)d_in[8];
    const float* W3  = (const float*)d_in[9];
    const float* b3  = (const float*)d_in[10];
    float* out = (float*)d_out;

    const int B   = in_sizes[0] / ZDIM;     // 4096
    const int nbc = B / BCHUNK;             // 128
    const int grid = (PDIM / PB) * nbc;     // 16 * 128 = 2048

    hipLaunchKernelGGL(pair_mlp_kernel, dim3(grid), dim3(PB), 0, stream,
                       x, W1, b1, g1, be1, W2, b2, g2, be2, W3, b3, out, nbc);
}

// Round 5
// 137.401 us; speedup vs baseline: 1.0008x; 1.0008x over previous
//
#include <hip/hip_runtime.h>
#include <cstddef>

#define ZDIM 64
#define PDIM 4096          // Z*Z
#define PB   256           // p's per block (= blockDim)
#define BCHUNK 16          // batch rows per block (8 row-pairs, fully unrolled)
#define NPAIR (BCHUNK/2)

typedef float v2f __attribute__((ext_vector_type(2)));

__device__ __forceinline__ v2f pkfma(v2f a, v2f b, v2f c) {
    return __builtin_elementwise_fma(a, b, c);
}
__device__ __forceinline__ v2f splat(float s) { v2f r; r.x = s; r.y = s; return r; }

// Odd Pade(7,6) tanh, |x| <= ~5.2 (validated in R3: passed with same data)
__device__ __forceinline__ v2f tanh2(v2f x) {
    v2f t = x * x;
    v2f np = t + splat(378.0f);
    np = pkfma(np, t, splat(17325.0f));
    np = pkfma(np, t, splat(135135.0f));
    v2f dp = pkfma(splat(28.0f), t, splat(3150.0f));
    dp = pkfma(dp, t, splat(62370.0f));
    dp = pkfma(dp, t, splat(135135.0f));
    v2f num = x * np;
    v2f r; r.x = __builtin_amdgcn_rcpf(dp.x); r.y = __builtin_amdgcn_rcpf(dp.y);
    return num * r;
}

__global__ void __launch_bounds__(PB, 3) pair_mlp_kernel(
    const float* __restrict__ x,
    const float* __restrict__ W1, const float* __restrict__ b1,
    const float* __restrict__ g1, const float* __restrict__ be1,
    const float* __restrict__ W2, const float* __restrict__ b2,
    const float* __restrict__ g2, const float* __restrict__ be2,
    const float* __restrict__ W3, const float* __restrict__ b3,
    float* __restrict__ out, int nbc)
{
    const int tid = threadIdx.x;
    const int pb  = blockIdx.x / nbc;          // p-tile (0..15)
    const int bc  = blockIdx.x - pb * nbc;     // batch chunk
    const int p   = pb * PB + tid;
    const int z   = __builtin_amdgcn_readfirstlane(p >> 6);  // wave-uniform
    const int zp  = p & 63;
    const int b0  = bc * BCHUNK;

    // -------- preload x for the whole chunk (no loads inside compute) --------
    // cv: per-lane, coalesced.  av: wave-uniform address -> s_load.
    const float* xrow = x + (size_t)b0 * ZDIM;
    float cvr[BCHUNK], avr[BCHUNK];
    #pragma unroll
    for (int r = 0; r < BCHUNK; ++r) {
        cvr[r] = xrow[r * ZDIM + zp];
        avr[r] = xrow[r * ZDIM + z];
    }

    // ---------------- load per-p weights ----------------
    const float4* W1v = reinterpret_cast<const float4*>(W1 + (size_t)p * 8);
    const float4 w1x = W1v[0];
    const float4 w1y = W1v[1];
    const float4 b1v  = reinterpret_cast<const float4*>(b1)[p];
    const float4 g1v  = reinterpret_cast<const float4*>(g1)[p];
    const float4 be1v = reinterpret_cast<const float4*>(be1)[p];
    float w2[4][4];
    {
        const float4* W2v = reinterpret_cast<const float4*>(W2 + (size_t)p * 16);
        #pragma unroll
        for (int i = 0; i < 4; ++i) {
            float4 r = W2v[i];
            w2[i][0] = r.x; w2[i][1] = r.y; w2[i][2] = r.z; w2[i][3] = r.w;
        }
    }
    const float4 b2v  = reinterpret_cast<const float4*>(b2)[p];
    const float4 g2v  = reinterpret_cast<const float4*>(g2)[p];
    const float4 be2v = reinterpret_cast<const float4*>(be2)[p];
    const float4 w3v  = reinterpret_cast<const float4*>(W3)[p];
    const float  b3s  = b3[p];

    const float w1a[4] = {w1x.x, w1x.y, w1x.z, w1x.w};
    const float w1b[4] = {w1y.x, w1y.y, w1y.z, w1y.w};
    const float b1a[4] = {b1v.x, b1v.y, b1v.z, b1v.w};
    const float g1a[4] = {g1v.x, g1v.y, g1v.z, g1v.w};
    const float be1a[4]= {be1v.x, be1v.y, be1v.z, be1v.w};
    const float b2a[4] = {b2v.x, b2v.y, b2v.z, b2v.w};
    const float g2a[4] = {g2v.x, g2v.y, g2v.z, g2v.w};
    const float be2a[4]= {be2v.x, be2v.y, be2v.z, be2v.w};
    const float w3a[4] = {w3v.x, w3v.y, w3v.z, w3v.w};

    // ---- fold LN1 affine into layer 2, LN2 affine into layer 3 (centered form) ----
    // k_j = rs * sum_i (t_i - m) * w2g[i][j] + b2p[j]
    float w2g[4][4], b2p[4];
    #pragma unroll
    for (int j = 0; j < 4; ++j) b2p[j] = b2a[j];
    #pragma unroll
    for (int i = 0; i < 4; ++i) {
        #pragma unroll
        for (int j = 0; j < 4; ++j) {
            w2g[i][j] = g1a[i] * w2[i][j];
            b2p[j] = __builtin_fmaf(be1a[i], w2[i][j], b2p[j]);
        }
    }
    float w3g[4], b3p = b3s;
    #pragma unroll
    for (int j = 0; j < 4; ++j) {
        w3g[j] = g2a[j] * w3a[j];
        b3p = __builtin_fmaf(be2a[j], w3a[j], b3p);
    }

    float* obase = out + (size_t)b0 * PDIM + p;

    // ---------------- fully unrolled: 8 row-pairs, zero loads ----------------
    #pragma unroll
    for (int k = 0; k < NPAIR; ++k) {
        v2f a2, c2;
        a2.x = avr[2 * k]; a2.y = avr[2 * k + 1];
        c2.x = cvr[2 * k]; c2.y = cvr[2 * k + 1];

        // layer 1 + tanh
        v2f t0 = tanh2(pkfma(a2, splat(w1a[0]), pkfma(c2, splat(w1b[0]), splat(b1a[0]))));
        v2f t1 = tanh2(pkfma(a2, splat(w1a[1]), pkfma(c2, splat(w1b[1]), splat(b1a[1]))));
        v2f t2 = tanh2(pkfma(a2, splat(w1a[2]), pkfma(c2, splat(w1b[2]), splat(b1a[2]))));
        v2f t3 = tanh2(pkfma(a2, splat(w1a[3]), pkfma(c2, splat(w1b[3]), splat(b1a[3]))));

        // LN1 moments
        v2f s1 = (t0 + t1) + (t2 + t3);
        v2f s2 = pkfma(t0, t0, pkfma(t1, t1, pkfma(t2, t2, t3 * t3)));
        v2f m  = s1 * 0.25f;
        v2f t1e = pkfma(s2, splat(0.25f), splat(1e-5f));
        v2f var = pkfma(s1 * splat(-0.0625f), s1, t1e);
        v2f rs; rs.x = __builtin_amdgcn_rsqf(var.x); rs.y = __builtin_amdgcn_rsqf(var.y);

        // centered
        v2f d0 = t0 - m, d1 = t1 - m, d2 = t2 - m, d3 = t3 - m;

        // layer 2 (LN1 folded) + tanh
        v2f u0, u1, u2, u3;
        {
            v2f acc;
            acc = pkfma(d0, splat(w2g[0][0]), pkfma(d1, splat(w2g[1][0]), pkfma(d2, splat(w2g[2][0]), d3 * splat(w2g[3][0]))));
            u0 = tanh2(pkfma(rs, acc, splat(b2p[0])));
            acc = pkfma(d0, splat(w2g[0][1]), pkfma(d1, splat(w2g[1][1]), pkfma(d2, splat(w2g[2][1]), d3 * splat(w2g[3][1]))));
            u1 = tanh2(pkfma(rs, acc, splat(b2p[1])));
            acc = pkfma(d0, splat(w2g[0][2]), pkfma(d1, splat(w2g[1][2]), pkfma(d2, splat(w2g[2][2]), d3 * splat(w2g[3][2]))));
            u2 = tanh2(pkfma(rs, acc, splat(b2p[2])));
            acc = pkfma(d0, splat(w2g[0][3]), pkfma(d1, splat(w2g[1][3]), pkfma(d2, splat(w2g[2][3]), d3 * splat(w2g[3][3]))));
            u3 = tanh2(pkfma(rs, acc, splat(b2p[3])));
        }

        // LN2 moments
        v2f q1 = (u0 + u1) + (u2 + u3);
        v2f q2 = pkfma(u0, u0, pkfma(u1, u1, pkfma(u2, u2, u3 * u3)));
        v2f m2  = q1 * 0.25f;
        v2f t2e = pkfma(q2, splat(0.25f), splat(1e-5f));
        v2f var2 = pkfma(q1 * splat(-0.0625f), q1, t2e);
        v2f rs2; rs2.x = __builtin_amdgcn_rsqf(var2.x); rs2.y = __builtin_amdgcn_rsqf(var2.y);

        v2f e0 = u0 - m2, e1 = u1 - m2, e2 = u2 - m2, e3 = u3 - m2;

        // layer 3 (LN2 folded) + sigmoid
        v2f acc3 = pkfma(e0, splat(w3g[0]), pkfma(e1, splat(w3g[1]), pkfma(e2, splat(w3g[2]), e3 * splat(w3g[3]))));
        v2f sarg = pkfma(rs2, acc3, splat(b3p));

        v2f q = sarg * splat(-1.4426950408889634f);
        v2f e; e.x = __builtin_amdgcn_exp2f(q.x); e.y = __builtin_amdgcn_exp2f(q.y);
        v2f ep1 = e + splat(1.0f);

        obase[(size_t)(2 * k) * PDIM]     = __builtin_amdgcn_rcpf(ep1.x);
        obase[(size_t)(2 * k + 1) * PDIM] = __builtin_amdgcn_rcpf(ep1.y);
    }
}

extern "C" void kernel_launch(void* const* d_in, const int* in_sizes, int n_in,
                              void* d_out, int out_size, void* d_ws, size_t ws_size,
                              hipStream_t stream) {
    const float* x   = (const float*)d_in[0];
    const float* W1  = (const float*)d_in[1];
    const float* b1  = (const float*)d_in[2];
    const float* g1  = (const float*)d_in[3];
    const float* be1 = (const float*)d_in[4];
    const float* W2  = (const float*)d_in[5];
    const float* b2  = (const float*)d_in[6];
    const float* g2  = (const float*)d_in[7];
    const float* be2 = (const float*)d_in[8];
    const float* W3  = (const float*)d_in[9];
    const float* b3  = (const float*)d_in[10];
    float* out = (float*)d_out;

    const int B   = in_sizes[0] / ZDIM;     // 4096
    const int nbc = B / BCHUNK;             // 256
    const int grid = (PDIM / PB) * nbc;     // 16 * 256 = 4096

    hipLaunchKernelGGL(pair_mlp_kernel, dim3(grid), dim3(PB), 0, stream,
                       x, W1, b1, g1, be1, W2, b2, g2, be2, W3, b3, out, nbc);
}